// Round 10
// baseline (539.273 us; speedup 1.0000x reference)
//
#include <hip/hip_runtime.h>
#include <math.h>
#include <stdint.h>

#define L_DIM 1024
#define C_DIM 128
#define H_DIM 512
#define B_DIM 16
#define LC (L_DIM * C_DIM)      // 131072
#define BLC (B_DIM * LC)        // 2097152

typedef __attribute__((ext_vector_type(8))) short short8;
typedef __attribute__((ext_vector_type(4))) float floatx4;

// ---------------- monotone float/bits -> ordered uint ----------------------
__device__ __forceinline__ unsigned fordbits(unsigned u) {
    return (u & 0x80000000u) ? ~u : (u | 0x80000000u);
}

// ---------------- truncation 3-way bf16 split: x = h + m + l + O(2^-24 x) --
__device__ __forceinline__ void split3(float x, unsigned& uh, unsigned& um,
                                       unsigned& ul) {
    uh = __float_as_uint(x);
    const float r1 = x - __uint_as_float(uh & 0xffff0000u);
    um = __float_as_uint(r1);
    const float r2 = r1 - __uint_as_float(um & 0xffff0000u);
    ul = __float_as_uint(r2);
}

__device__ __forceinline__ float gelu_fast(float x) {
    const float g = 0.7978845608028654f * (x + 0.044715f * x * x * x);
    const float e = __expf(2.0f * g);
    const float t = 1.0f - 2.0f / (e + 1.0f);
    return 0.5f * x * (1.0f + t);
}

// ---------------- W pre-split into MFMA B-frag layout (h/m/l bf16) ---------
__global__ __launch_bounds__(256) void wsplit_kernel(
    const float* __restrict__ W1, const float* __restrict__ W2,
    unsigned short* __restrict__ W1h, unsigned short* __restrict__ W1m,
    unsigned short* __restrict__ W1l, unsigned short* __restrict__ W2h,
    unsigned short* __restrict__ W2m, unsigned short* __restrict__ W2l) {
    const int t = blockIdx.x * 256 + threadIdx.x;  // < 131072
    unsigned uh, um, ul;
    if (t < 65536) {
        const int j = t & 7, lane = (t >> 3) & 63, nt = (t >> 9) & 31,
                  kt = (t >> 14) & 3;
        const int k = kt * 32 + (lane >> 4) * 8 + j;
        const int n = nt * 16 + (lane & 15);
        split3(W1[k * 512 + n], uh, um, ul);
        W1h[t] = (unsigned short)(uh >> 16);
        W1m[t] = (unsigned short)(um >> 16);
        W1l[t] = (unsigned short)(ul >> 16);
    } else {
        const int t2 = t - 65536;
        const int j = t2 & 7, lane = (t2 >> 3) & 63, nt = (t2 >> 9) & 7,
                  kt = (t2 >> 12) & 15;
        const int k = kt * 32 + (lane >> 4) * 8 + j;
        const int n = nt * 16 + (lane & 15);
        split3(W2[k * 128 + n], uh, um, ul);
        W2h[t2] = (unsigned short)(uh >> 16);
        W2m[t2] = (unsigned short)(um >> 16);
        W2l[t2] = (unsigned short)(ul >> 16);
    }
}

// 6-term bf16x3 MFMA accumulate (small terms first); error ~2^-24
#define MFMA6(AH, AM, AL, BH, BM, BL, ACC)                                    \
    ACC = __builtin_amdgcn_mfma_f32_16x16x32_bf16(AL, BH, ACC, 0, 0, 0);      \
    ACC = __builtin_amdgcn_mfma_f32_16x16x32_bf16(AM, BM, ACC, 0, 0, 0);      \
    ACC = __builtin_amdgcn_mfma_f32_16x16x32_bf16(AH, BL, ACC, 0, 0, 0);      \
    ACC = __builtin_amdgcn_mfma_f32_16x16x32_bf16(AM, BH, ACC, 0, 0, 0);      \
    ACC = __builtin_amdgcn_mfma_f32_16x16x32_bf16(AH, BM, ACC, 0, 0, 0);      \
    ACC = __builtin_amdgcn_mfma_f32_16x16x32_bf16(AH, BH, ACC, 0, 0, 0);

// XOR-swizzled LDS address for A-tiles: 16 rows x 128 cols of ushort.
__device__ __forceinline__ int swz(int row, int col) {
    return row * 128 + ((((col >> 3) ^ (row & 15))) << 3) + (col & 7);
}

// ---------------- fused MLP (+ previous step's DPM update when UPD) --------
// Block: 512 thr (8 waves), M=16 rows (16 b x 1 l), grid 1024 -> 4 blocks/CU
// (R9's grid 512 = 2 blocks/CU hard-capped occupancy at 50%; measured 38%
// with MfmaUtil 14% = latency-bound). LDS 24.3KB, VGPR ~60 -> 32 waves/CU.
// UPD=0 also materializes z = zin (z_init) -- replaces the memcpy dispatch.
template <int UPD>
__global__ __launch_bounds__(512, 4) void mlp_kernel(
    const float* __restrict__ zin, float* __restrict__ z,
    const float* __restrict__ y, const float* __restrict__ mk,
    const unsigned short* __restrict__ W1h, const unsigned short* __restrict__ W1m,
    const unsigned short* __restrict__ W1l, const unsigned short* __restrict__ W2h,
    const unsigned short* __restrict__ W2m, const unsigned short* __restrict__ W2l,
    const float* __restrict__ b1, const float* __restrict__ tw,
    const float* __restrict__ b2, float t_feat,
    float* __restrict__ eps_buf, float* __restrict__ ent,
    const float* __restrict__ cA, const float* __restrict__ cB,
    const float* __restrict__ cG, float* __restrict__ accum) {
    __shared__ unsigned short zA[3][2048];  // swizzled [row<16][col<128]
    __shared__ unsigned short hA[3][2048];  // swizzled h quarter
    __shared__ float red1[8], red2[8];
    const int tid = threadIdx.x;
    const int w = tid >> 6, lane = tid & 63;
    const int quad = lane >> 4, m16 = lane & 15;
    const int l0 = blockIdx.x;  // one l per block

    // ---- phase 1: (coeff-map update / init-copy) + stats + stage z ----
    float s1 = 0.f, s2 = 0.f;
    {
        const int f = tid * 4;               // 0..2044
        const int r_ = f >> 7, cb = f & 127; // r_ = b
        const size_t g = ((size_t)r_ * 1024 + l0) * 128 + cb;
        float4 zv = *(const float4*)(zin + g);
        const float4 yv = *(const float4*)(y + g);
        const float4 mv = *(const float4*)(mk + g);
        if (UPD) {
            const float4 ev = *(const float4*)(eps_buf + g);
            const int pix = l0 * 128 + cb;
            const float4 a4 = *(const float4*)(cA + pix);
            const float4 b4 = *(const float4*)(cB + pix);
            const float4 g4 = *(const float4*)(cG + pix);
            zv.x = a4.x * zv.x - b4.x * ev.x - g4.x * ((zv.x - yv.x) * mv.x);
            zv.y = a4.y * zv.y - b4.y * ev.y - g4.y * ((zv.y - yv.y) * mv.y);
            zv.z = a4.z * zv.z - b4.z * ev.z - g4.z * ((zv.z - yv.z) * mv.z);
            zv.w = a4.w * zv.w - b4.w * ev.w - g4.w * ((zv.w - yv.w) * mv.w);
        }
        *(float4*)(z + g) = zv;  // UPD: updated value; !UPD: init copy
        float oe;
        oe = (zv.x - yv.x) * mv.x; s1 += oe; s2 += oe * oe;
        oe = (zv.y - yv.y) * mv.y; s1 += oe; s2 += oe * oe;
        oe = (zv.z - yv.z) * mv.z; s1 += oe; s2 += oe * oe;
        oe = (zv.w - yv.w) * mv.w; s1 += oe; s2 += oe * oe;

        const int base = swz(r_, cb);
        const float xs[4] = {zv.x, zv.y, zv.z, zv.w};
        ushort4 vh, vm, vl;
        unsigned uh, um, ul;
        split3(xs[0], uh, um, ul); vh.x = uh >> 16; vm.x = um >> 16; vl.x = ul >> 16;
        split3(xs[1], uh, um, ul); vh.y = uh >> 16; vm.y = um >> 16; vl.y = ul >> 16;
        split3(xs[2], uh, um, ul); vh.z = uh >> 16; vm.z = um >> 16; vl.z = ul >> 16;
        split3(xs[3], uh, um, ul); vh.w = uh >> 16; vm.w = um >> 16; vl.w = ul >> 16;
        *(ushort4*)(&zA[0][base]) = vh;
        *(ushort4*)(&zA[1][base]) = vm;
        *(ushort4*)(&zA[2][base]) = vl;
    }
#pragma unroll
    for (int off = 32; off; off >>= 1) {
        s1 += __shfl_down(s1, off);
        s2 += __shfl_down(s2, off);
    }
    if (lane == 0) { red1[w] = s1; red2[w] = s2; }
    __syncthreads();  // staging + red complete
    if (tid == 0) {
        float a1 = 0.f, a2 = 0.f;
#pragma unroll
        for (int i = 0; i < 8; ++i) { a1 += red1[i]; a2 += red2[i]; }
        atomicAdd(&accum[0], a1);
        atomicAdd(&accum[1], a2);
    }

    // ---- GEMM1 (all H): acc1[q], wave's nt1 = q*8 + w ----
    floatx4 acc1[4];
#pragma unroll
    for (int i = 0; i < 4; ++i) acc1[i] = (floatx4){0.f, 0.f, 0.f, 0.f};

#pragma unroll
    for (int kt = 0; kt < 4; ++kt) {
        const int fb = swz(m16, kt * 32 + quad * 8);
        const short8 Ah = *(const short8*)(&zA[0][fb]);
        const short8 Am = *(const short8*)(&zA[1][fb]);
        const short8 Al = *(const short8*)(&zA[2][fb]);
#pragma unroll
        for (int q = 0; q < 4; ++q) {
            const size_t off = ((size_t)(kt * 32 + q * 8 + w) * 64 + lane) * 8;
            const short8 bh = *(const short8*)(W1h + off);
            const short8 bm = *(const short8*)(W1m + off);
            const short8 bl = *(const short8*)(W1l + off);
            floatx4 a = acc1[q];
            MFMA6(Ah, Am, Al, bh, bm, bl, a);
            acc1[q] = a;
        }
    }

    // ---- quarter phases: gelu+split h -> swizzled LDS, GEMM2 partial-K ----
    floatx4 acc2 = (floatx4){0.f, 0.f, 0.f, 0.f};

    for (int q = 0; q < 4; ++q) {
        __syncthreads();  // prior quarter's hA reads (or GEMM1/staging) done
        {
            const int colg = q * 128 + w * 16 + m16;
            const float bb = b1[colg] + t_feat * tw[colg];
            const int kcol = w * 16 + m16;  // quarter-local k col
#pragma unroll
            for (int r = 0; r < 4; ++r) {
                const float x = gelu_fast(acc1[q][r] + bb);
                unsigned uh, um, ul;
                split3(x, uh, um, ul);
                const int idx = swz(quad * 4 + r, kcol);
                hA[0][idx] = (unsigned short)(uh >> 16);
                hA[1][idx] = (unsigned short)(um >> 16);
                hA[2][idx] = (unsigned short)(ul >> 16);
            }
        }
        __syncthreads();

#pragma unroll
        for (int ktl = 0; ktl < 4; ++ktl) {
            const int fb = swz(m16, ktl * 32 + quad * 8);
            const short8 Ah2 = *(const short8*)(&hA[0][fb]);
            const short8 Am2 = *(const short8*)(&hA[1][fb]);
            const short8 Al2 = *(const short8*)(&hA[2][fb]);
            const size_t off =
                ((size_t)((q * 4 + ktl) * 8 + w) * 64 + lane) * 8;
            const short8 bh = *(const short8*)(W2h + off);
            const short8 bm = *(const short8*)(W2m + off);
            const short8 bl = *(const short8*)(W2l + off);
            MFMA6(Ah2, Am2, Al2, bh, bm, bl, acc2);
        }
    }

    // ---- epilogue: +b2, write eps, ent = mean_b |eps| ----
    {
        const int col = w * 16 + m16;
        const float bb2 = b2[col];
        float pa = 0.f;
#pragma unroll
        for (int r = 0; r < 4; ++r) {
            const float e = acc2[r] + bb2;
            const int b = quad * 4 + r;
            eps_buf[((size_t)b * 1024 + l0) * 128 + col] = e;
            pa += fabsf(e);
        }
        pa += __shfl_xor(pa, 16);
        pa += __shfl_xor(pa, 32);
        if (quad == 0) ent[l0 * 128 + col] = pa * (1.0f / 16.0f);
    }
}

// ------- monotone-counter grid barrier: NO threadfence, NO release flag ----
__device__ __forceinline__ void gbar(unsigned* c, unsigned target) {
    __syncthreads();
    if (threadIdx.x == 0) {
        atomicAdd(c, 1u);
        while (atomicAdd(c, 0u) < target) __builtin_amdgcn_s_sleep(1);
    }
    __syncthreads();
}

// -------- fused select: pools + radix top-k + per-pixel update coeffs ------
__global__ __launch_bounds__(256, 1) void select_kernel(
    const float* __restrict__ ent, float* __restrict__ p1,
    float* __restrict__ p2, float* __restrict__ p3,
    unsigned* __restrict__ ghist, unsigned* __restrict__ ctr,
    unsigned* __restrict__ gprefix, float* __restrict__ cA,
    float* __restrict__ cB, float* __restrict__ cG,
    const float* __restrict__ accum_si, float base_a, float base_b,
    float h_lam, int si) {
    __shared__ float dataL[2048];
    __shared__ unsigned hist[4][256];
    __shared__ unsigned sh[256];
    __shared__ unsigned sh_dig, sh_krem;
    const int bid = blockIdx.x, t = threadIdx.x;
    const int gid = bid * 256 + t;
    unsigned* cc = &ctr[si];

    // ---- stage block-local data (+ publish pools) ----
    int scale, nloc;
    unsigned K;
    if (bid < 64) {
        scale = 0; nloc = 2048; K = 26214u;
        const int base = bid * 2048;
        for (int i = t; i < 2048; i += 256) dataL[i] = ent[base + i];
    } else if (bid < 80) {
        scale = 1; nloc = 2048; K = 6553u;
        const int base = (bid - 64) * 2048;
        for (int i = t; i < 2048; i += 256) {
            const int idx = base + i;
            const int r = idx >> 6, c = idx & 63;
            float s = 0.f;
#pragma unroll
            for (int ii = 0; ii < 2; ++ii)
#pragma unroll
                for (int jj = 0; jj < 2; ++jj)
                    s += ent[((r * 2 + ii) << 7) + c * 2 + jj];
            const float v = s * 0.25f;
            dataL[i] = v;
            atomicExch((unsigned*)&p1[idx], __float_as_uint(v));
        }
    } else if (bid < 84) {
        scale = 2; nloc = 2048; K = 1638u;
        const int base = (bid - 80) * 2048;
        for (int i = t; i < 2048; i += 256) {
            const int idx = base + i;
            const int r = idx >> 5, c = idx & 31;
            float s = 0.f;
#pragma unroll
            for (int ii = 0; ii < 4; ++ii)
#pragma unroll
                for (int jj = 0; jj < 4; ++jj)
                    s += ent[((r * 4 + ii) << 7) + c * 4 + jj];
            const float v = s * 0.0625f;
            dataL[i] = v;
            atomicExch((unsigned*)&p2[idx], __float_as_uint(v));
        }
    } else {
        scale = 3; nloc = 512; K = 409u;
        const int base = (bid - 84) * 512;
        for (int i = t; i < 512; i += 256) {
            const int idx = base + i;
            const int r = idx >> 4, c = idx & 15;
            float s = 0.f;
#pragma unroll
            for (int ii = 0; ii < 8; ++ii)
#pragma unroll
                for (int jj = 0; jj < 8; ++jj)
                    s += ent[((r * 8 + ii) << 7) + c * 8 + jj];
            const float v = s * (1.0f / 64.0f);
            dataL[i] = v;
            atomicExch((unsigned*)&p3[idx], __float_as_uint(v));
        }
    }
    __syncthreads();  // dataL ready (block-local)

    // ---- 4-pass radix select over LDS data ----
    const int wv = t >> 6;
    unsigned prefix = 0u, krem = K;
    for (int p = 0; p < 4; ++p) {
        const int shift = 24 - 8 * p;
        const unsigned hmask = p ? (0xFFFFFFFFu << (shift + 8)) : 0u;
#pragma unroll
        for (int i = t; i < 1024; i += 256) ((unsigned*)hist)[i] = 0u;
        __syncthreads();
        for (int i = t; i < nloc; i += 256) {
            const unsigned u = fordbits(__float_as_uint(dataL[i]));
            if ((u & hmask) == (prefix & hmask))
                atomicAdd(&hist[wv][(u >> shift) & 255u], 1u);
        }
        __syncthreads();
        const unsigned c = hist[0][t] + hist[1][t] + hist[2][t] + hist[3][t];
        unsigned* gh = &ghist[((si * 4 + p) * 4 + scale) * 256];
        if (c) atomicAdd(&gh[t], c);
        gbar(cc, 88u * (unsigned)(p + 1));
        sh[t] = atomicAdd(&gh[t], 0u);
        __syncthreads();
#pragma unroll
        for (int off = 1; off < 256; off <<= 1) {
            const unsigned v = (t + off < 256) ? sh[t + off] : 0u;
            __syncthreads();
            sh[t] += v;
            __syncthreads();
        }
        const unsigned suf = sh[t];
        const unsigned sufn = (t < 255) ? sh[t + 1] : 0u;
        if (suf >= krem && sufn < krem) {  // unique crossing
            sh_dig = (unsigned)t;
            sh_krem = krem - sufn;
        }
        __syncthreads();
        prefix |= (sh_dig << shift);
        krem = sh_krem;
        __syncthreads();
    }
    // one owner block per scale publishes its threshold
    if (t == 0 && (bid == 0 || bid == 64 || bid == 80 || bid == 84))
        atomicExch(&gprefix[scale], prefix);
    gbar(cc, 88u * 5u);

    // ---- coeff maps: per pixel, z_new = cA*z - cB*eps - cG*(z-y)*m ----
    const unsigned t0 = atomicAdd(&gprefix[0], 0u);
    const unsigned t1 = atomicAdd(&gprefix[1], 0u);
    const unsigned t2 = atomicAdd(&gprefix[2], 0u);
    const unsigned t3 = atomicAdd(&gprefix[3], 0u);
    const float mean = accum_si[0] * (1.0f / (float)BLC);
    const float var = accum_si[1] * (1.0f / (float)BLC) - mean * mean;
    const float vinv = 1.0f / (var + 1e-8f);

    for (int i = gid; i < LC; i += 22528) {
        const int l = i >> 7, c = i & 127;
        float ent_v = 0.f;
        bool sel = false;
        const float v0 = ent[i];
        if (fordbits(__float_as_uint(v0)) >= t0) { ent_v = v0; sel = true; }
        else {
            const float v1 = __uint_as_float(atomicAdd(
                (unsigned*)&p1[((l >> 1) << 6) + (c >> 1)], 0u));
            if (fordbits(__float_as_uint(v1)) >= t1) { ent_v = v1; sel = true; }
            else {
                const float v2 = __uint_as_float(atomicAdd(
                    (unsigned*)&p2[((l >> 2) << 5) + (c >> 2)], 0u));
                if (fordbits(__float_as_uint(v2)) >= t2) { ent_v = v2; sel = true; }
                else {
                    const float v3 = __uint_as_float(atomicAdd(
                        (unsigned*)&p3[((l >> 3) << 4) + (c >> 3)], 0u));
                    if (fordbits(__float_as_uint(v3)) >= t3) { ent_v = v3; sel = true; }
                }
            }
        }
        if (sel) {
            float corr;
            if (ent_v > 0.5f)
                corr = 1.0f + h_lam + h_lam * h_lam * (1.0f / 3.0f);
            else if (ent_v > 0.1f)
                corr = 1.0f + 0.5f * h_lam;
            else
                corr = 1.0f;
            cA[i] = base_a;
            cB[i] = base_b * corr;
            cG[i] = (2.0f * ent_v / (ent_v + 1.0f)) * vinv;
        } else {
            cA[i] = 1.0f;
            cB[i] = 0.f;
            cG[i] = 0.f;
        }
    }
}

// ---------------- standalone final update (coeff-map streaming) ------------
__global__ __launch_bounds__(256) void update_kernel(
    float* __restrict__ z, const float* __restrict__ y,
    const float* __restrict__ mk, const float* __restrict__ eps,
    const float* __restrict__ cA, const float* __restrict__ cB,
    const float* __restrict__ cG) {
    const int idx = blockIdx.x * 256 + threadIdx.x;  // < BLC
    const int p = idx & (LC - 1);
    const float zi = z[idx];
    z[idx] = cA[p] * zi - cB[p] * eps[idx] - cG[p] * ((zi - y[idx]) * mk[idx]);
}

// ---------------------------------------------------------------------------
extern "C" void kernel_launch(void* const* d_in, const int* in_sizes, int n_in,
                              void* d_out, int out_size, void* d_ws,
                              size_t ws_size, hipStream_t stream) {
    const float* y_obs = (const float*)d_in[0];
    const float* mask = (const float*)d_in[1];
    const float* z_init = (const float*)d_in[2];
    const float* W1 = (const float*)d_in[3];
    const float* b1 = (const float*)d_in[4];
    const float* W2 = (const float*)d_in[5];
    const float* b2 = (const float*)d_in[6];
    const float* tw = (const float*)d_in[7];
    float* z = (float*)d_out;
    float* ws = (float*)d_ws;

    // workspace layout (float offsets)
    float* eps = ws;                                 // 2097152
    float* ent = ws + 2097152;                       // 131072
    float* p1 = ws + 2228224;                        // 32768
    float* p2 = ws + 2260992;                        // 8192
    float* p3 = ws + 2269184;                        // 2048
    float* cA = ws + 2271232;                        // 131072
    float* cB = ws + 2402304;                        // 131072
    float* cG = ws + 2533376;                        // 131072
    // zero block: ghist[16384] + ctr[4] + accum[8] + gprefix[4]
    unsigned* ghist = (unsigned*)(ws + 2664448);     // 16384 u32
    unsigned* ctr = (unsigned*)(ws + 2680832);       // 4
    float* accum = ws + 2680836;                     // 8 (2 per step)
    unsigned* gprefix = (unsigned*)(ws + 2680844);   // 4
    unsigned short* W1h = (unsigned short*)(ws + 2680848);  // 65536 u16 each
    unsigned short* W1m = (unsigned short*)(ws + 2713616);
    unsigned short* W1l = (unsigned short*)(ws + 2746384);
    unsigned short* W2h = (unsigned short*)(ws + 2779152);
    unsigned short* W2m = (unsigned short*)(ws + 2811920);
    unsigned short* W2l = (unsigned short*)(ws + 2844688);

    // diffusion schedule in fp32 (input-independent)
    float alpha_[1000], sigma_[1000], lam_[1000];
    {
        float ac = 1.0f;
        for (int i = 0; i < 1000; ++i) {
            const float beta = 1e-4f + (0.02f - 1e-4f) * ((float)i / 999.0f);
            ac = ac * (1.0f - beta);
            alpha_[i] = sqrtf(ac);
            sigma_[i] = sqrtf(1.0f - ac);
            lam_[i] = logf(alpha_[i]) - logf(sigma_[i]);
        }
    }
    float tf[4], hl[4], ba[4], bb[4];
    for (int si = 0; si < 4; ++si) {
        const int k = 999 - si * 250;
        const int kp = (k - 250 > 0) ? (k - 250) : 0;
        tf[si] = (float)k / 1000.0f;
        hl[si] = lam_[kp] - lam_[k];
        ba[si] = alpha_[kp] / alpha_[k];
        bb[si] = sigma_[kp] * (expf(hl[si]) - 1.0f);
    }

    hipMemsetAsync(ghist, 0, (16384 + 4 + 8 + 4) * sizeof(unsigned), stream);
    wsplit_kernel<<<512, 256, 0, stream>>>(W1, W2, W1h, W1m, W1l, W2h, W2m,
                                           W2l);

    for (int si = 0; si < 4; ++si) {
        if (si == 0) {
            mlp_kernel<0><<<1024, 512, 0, stream>>>(
                z_init, z, y_obs, mask, W1h, W1m, W1l, W2h, W2m, W2l, b1, tw,
                b2, tf[0], eps, ent, cA, cB, cG, accum);
        } else {
            mlp_kernel<1><<<1024, 512, 0, stream>>>(
                z, z, y_obs, mask, W1h, W1m, W1l, W2h, W2m, W2l, b1, tw, b2,
                tf[si], eps, ent, cA, cB, cG, accum + 2 * si);
        }
        select_kernel<<<88, 256, 0, stream>>>(
            ent, p1, p2, p3, ghist, ctr, gprefix, cA, cB, cG,
            accum + 2 * si, ba[si], bb[si], hl[si], si);
    }
    update_kernel<<<8192, 256, 0, stream>>>(z, y_obs, mask, eps, cA, cB, cG);
}

// Round 12
// 466.303 us; speedup vs baseline: 1.1565x; 1.1565x over previous
//
#include <hip/hip_runtime.h>
#include <math.h>
#include <stdint.h>

#define L_DIM 1024
#define C_DIM 128
#define H_DIM 512
#define B_DIM 16
#define LC (L_DIM * C_DIM)      // 131072
#define BLC (B_DIM * LC)        // 2097152

typedef __attribute__((ext_vector_type(8))) short short8;
typedef __attribute__((ext_vector_type(4))) float floatx4;

// ---------------- monotone float/bits -> ordered uint ----------------------
__device__ __forceinline__ unsigned fordbits(unsigned u) {
    return (u & 0x80000000u) ? ~u : (u | 0x80000000u);
}

// ---------------- truncation 3-way bf16 split: x = h + m + l + O(2^-24 x) --
__device__ __forceinline__ void split3(float x, unsigned& uh, unsigned& um,
                                       unsigned& ul) {
    uh = __float_as_uint(x);
    const float r1 = x - __uint_as_float(uh & 0xffff0000u);
    um = __float_as_uint(r1);
    const float r2 = r1 - __uint_as_float(um & 0xffff0000u);
    ul = __float_as_uint(r2);
}

__device__ __forceinline__ float gelu_fast(float x) {
    const float g = 0.7978845608028654f * (x + 0.044715f * x * x * x);
    const float e = __expf(2.0f * g);
    const float t = 1.0f - 2.0f / (e + 1.0f);
    return 0.5f * x * (1.0f + t);
}

// ---------------- W pre-split into MFMA B-frag layout (h/m/l bf16) ---------
__global__ __launch_bounds__(256) void wsplit_kernel(
    const float* __restrict__ W1, const float* __restrict__ W2,
    unsigned short* __restrict__ W1h, unsigned short* __restrict__ W1m,
    unsigned short* __restrict__ W1l, unsigned short* __restrict__ W2h,
    unsigned short* __restrict__ W2m, unsigned short* __restrict__ W2l) {
    const int t = blockIdx.x * 256 + threadIdx.x;  // < 131072
    unsigned uh, um, ul;
    if (t < 65536) {
        const int j = t & 7, lane = (t >> 3) & 63, nt = (t >> 9) & 31,
                  kt = (t >> 14) & 3;
        const int k = kt * 32 + (lane >> 4) * 8 + j;
        const int n = nt * 16 + (lane & 15);
        split3(W1[k * 512 + n], uh, um, ul);
        W1h[t] = (unsigned short)(uh >> 16);
        W1m[t] = (unsigned short)(um >> 16);
        W1l[t] = (unsigned short)(ul >> 16);
    } else {
        const int t2 = t - 65536;
        const int j = t2 & 7, lane = (t2 >> 3) & 63, nt = (t2 >> 9) & 7,
                  kt = (t2 >> 12) & 15;
        const int k = kt * 32 + (lane >> 4) * 8 + j;
        const int n = nt * 16 + (lane & 15);
        split3(W2[k * 128 + n], uh, um, ul);
        W2h[t2] = (unsigned short)(uh >> 16);
        W2m[t2] = (unsigned short)(um >> 16);
        W2l[t2] = (unsigned short)(ul >> 16);
    }
}

// 6-term bf16x3 MFMA accumulate (small terms first); error ~2^-24
#define MFMA6(AH, AM, AL, BH, BM, BL, ACC)                                    \
    ACC = __builtin_amdgcn_mfma_f32_16x16x32_bf16(AL, BH, ACC, 0, 0, 0);      \
    ACC = __builtin_amdgcn_mfma_f32_16x16x32_bf16(AM, BM, ACC, 0, 0, 0);      \
    ACC = __builtin_amdgcn_mfma_f32_16x16x32_bf16(AH, BL, ACC, 0, 0, 0);      \
    ACC = __builtin_amdgcn_mfma_f32_16x16x32_bf16(AM, BH, ACC, 0, 0, 0);      \
    ACC = __builtin_amdgcn_mfma_f32_16x16x32_bf16(AH, BM, ACC, 0, 0, 0);      \
    ACC = __builtin_amdgcn_mfma_f32_16x16x32_bf16(AH, BH, ACC, 0, 0, 0);

// read a split A-fragment (row, k-base) from packed LDS (R5/R6-benched path)
__device__ __forceinline__ void ldsA(const unsigned* hm,
                                     const unsigned short* lr, int row,
                                     int kbase, short8& Ah, short8& Am,
                                     short8& Al) {
    const unsigned* p = &hm[row * 132 + kbase];
    const uint4 a = *(const uint4*)p;
    const uint4 b = *(const uint4*)(p + 4);
    union { short8 v; unsigned u[4]; } ah, am;
    ah.u[0] = (a.x & 0xffffu) | (a.y << 16);
    ah.u[1] = (a.z & 0xffffu) | (a.w << 16);
    ah.u[2] = (b.x & 0xffffu) | (b.y << 16);
    ah.u[3] = (b.z & 0xffffu) | (b.w << 16);
    am.u[0] = (a.x >> 16) | (a.y & 0xffff0000u);
    am.u[1] = (a.z >> 16) | (a.w & 0xffff0000u);
    am.u[2] = (b.x >> 16) | (b.y & 0xffff0000u);
    am.u[3] = (b.z >> 16) | (b.w & 0xffff0000u);
    Ah = ah.v;
    Am = am.v;
    Al = *(const short8*)(&lr[row * 136 + kbase]);
}

// ---------------- fused MLP (+ previous step's DPM update when UPD) --------
// EXACT R5-response GEMM body (benched R6: 45.1us, MfmaUtil 22%, absmax 256):
// 512 thr, M=32 rows (16b x 2l), grid 512, packed hm|l LDS, halves-
// interleaved GEMM1/GEMM2, GEMM2 A-rows il*16+m16 with nt2 = w (R11's
// (ila+il)*16 row index was an out-of-bounds bug -> absmax 184832).
// Phase 1: streaming coeff-map update (R8-proven) + z-init fusion.
template <int UPD>
__global__ __launch_bounds__(512, 2) void mlp_kernel(
    const float* __restrict__ zin, float* __restrict__ z,
    const float* __restrict__ y, const float* __restrict__ mk,
    const unsigned short* __restrict__ W1h, const unsigned short* __restrict__ W1m,
    const unsigned short* __restrict__ W1l, const unsigned short* __restrict__ W2h,
    const unsigned short* __restrict__ W2m, const unsigned short* __restrict__ W2l,
    const float* __restrict__ b1, const float* __restrict__ tw,
    const float* __restrict__ b2, float t_feat,
    float* __restrict__ eps_buf, float* __restrict__ ent,
    const float* __restrict__ cA, const float* __restrict__ cB,
    const float* __restrict__ cG, float* __restrict__ accum) {
    __shared__ unsigned lds_hm[32 * 132];        // z: h|m packed
    __shared__ unsigned short lds_l[32 * 136];   // z: l
    __shared__ unsigned h_hm[32 * 132];          // h quarter: h|m packed
    __shared__ unsigned short h_l[32 * 136];     // h quarter: l
    __shared__ float red1[8], red2[8];
    const int tid = threadIdx.x;
    const int w = tid >> 6, lane = tid & 63;
    const int quad = lane >> 4, m16 = lane & 15;
    const int l0 = blockIdx.x * 2;

    // ---- phase 1: (coeff-map update / init-copy) + stats + stage z ----
    float s1 = 0.f, s2 = 0.f;
#pragma unroll
    for (int e = 0; e < 2; ++e) {
        const int f = tid * 8 + e * 4;  // 0..4095
        const int r_ = f >> 7, cb = f & 127;
        const int b = r_ & 15, il = r_ >> 4, l = l0 + il;
        const size_t g = ((size_t)b * 1024 + l) * 128 + cb;
        float4 zv = *(const float4*)(zin + g);
        const float4 yv = *(const float4*)(y + g);
        const float4 mv = *(const float4*)(mk + g);
        if (UPD) {
            const float4 ev = *(const float4*)(eps_buf + g);
            const int pix = l * 128 + cb;
            const float4 a4 = *(const float4*)(cA + pix);
            const float4 b4 = *(const float4*)(cB + pix);
            const float4 g4 = *(const float4*)(cG + pix);
            zv.x = a4.x * zv.x - b4.x * ev.x - g4.x * ((zv.x - yv.x) * mv.x);
            zv.y = a4.y * zv.y - b4.y * ev.y - g4.y * ((zv.y - yv.y) * mv.y);
            zv.z = a4.z * zv.z - b4.z * ev.z - g4.z * ((zv.z - yv.z) * mv.z);
            zv.w = a4.w * zv.w - b4.w * ev.w - g4.w * ((zv.w - yv.w) * mv.w);
        }
        *(float4*)(z + g) = zv;  // UPD: updated value; !UPD: init copy
        float oe;
        oe = (zv.x - yv.x) * mv.x; s1 += oe; s2 += oe * oe;
        oe = (zv.y - yv.y) * mv.y; s1 += oe; s2 += oe * oe;
        oe = (zv.z - yv.z) * mv.z; s1 += oe; s2 += oe * oe;
        oe = (zv.w - yv.w) * mv.w; s1 += oe; s2 += oe * oe;

        const float xs[4] = {zv.x, zv.y, zv.z, zv.w};
#pragma unroll
        for (int i = 0; i < 4; ++i) {
            unsigned uh, um, ul;
            split3(xs[i], uh, um, ul);
            lds_hm[r_ * 132 + cb + i] = (uh >> 16) | (um & 0xffff0000u);
            lds_l[r_ * 136 + cb + i] = (unsigned short)(ul >> 16);
        }
    }
#pragma unroll
    for (int off = 32; off; off >>= 1) {
        s1 += __shfl_down(s1, off);
        s2 += __shfl_down(s2, off);
    }
    if (lane == 0) { red1[w] = s1; red2[w] = s2; }
    __syncthreads();  // staging + red arrays complete
    if (tid == 0) {
        float a1 = 0.f, a2 = 0.f;
#pragma unroll
        for (int i = 0; i < 8; ++i) { a1 += red1[i]; a2 += red2[i]; }
        atomicAdd(&accum[0], a1);
        atomicAdd(&accum[1], a2);
    }

    // ---- GEMM pipeline (exact R5-benched structure) ----
    floatx4 acc2[2];
    acc2[0] = (floatx4){0.f, 0.f, 0.f, 0.f};
    acc2[1] = (floatx4){0.f, 0.f, 0.f, 0.f};

    for (int hf = 0; hf < 2; ++hf) {
        floatx4 acc1[4];  // [s*2 + il]
#pragma unroll
        for (int i = 0; i < 4; ++i) acc1[i] = (floatx4){0.f, 0.f, 0.f, 0.f};

#pragma unroll
        for (int kt = 0; kt < 4; ++kt) {
            short8 Ah[2], Am[2], Al[2];
#pragma unroll
            for (int il = 0; il < 2; ++il)
                ldsA(lds_hm, lds_l, il * 16 + m16, kt * 32 + quad * 8,
                     Ah[il], Am[il], Al[il]);
#pragma unroll
            for (int s = 0; s < 2; ++s) {
                const int nt1 = (hf * 2 + s) * 8 + w;
                const size_t off = ((size_t)(kt * 32 + nt1) * 64 + lane) * 8;
                const short8 bh = *(const short8*)(W1h + off);
                const short8 bm = *(const short8*)(W1m + off);
                const short8 bl = *(const short8*)(W1l + off);
#pragma unroll
                for (int il = 0; il < 2; ++il) {
                    floatx4 a = acc1[s * 2 + il];
                    MFMA6(Ah[il], Am[il], Al[il], bh, bm, bl, a);
                    acc1[s * 2 + il] = a;
                }
            }
        }

#pragma unroll
        for (int s = 0; s < 2; ++s) {
            const int q = hf * 2 + s;
            __syncthreads();  // previous quarter's h-LDS reads done
            {
                const int coll = w * 16 + m16;     // quarter-local col
                const int colg = q * 128 + coll;   // global H col
                const float bb = b1[colg] + t_feat * tw[colg];
#pragma unroll
                for (int il = 0; il < 2; ++il) {
#pragma unroll
                    for (int r = 0; r < 4; ++r) {
                        const float x = gelu_fast(acc1[s * 2 + il][r] + bb);
                        unsigned uh, um, ul;
                        split3(x, uh, um, ul);
                        const int row = il * 16 + quad * 4 + r;
                        h_hm[row * 132 + coll] = (uh >> 16) | (um & 0xffff0000u);
                        h_l[row * 136 + coll] = (unsigned short)(ul >> 16);
                    }
                }
            }
            __syncthreads();

#pragma unroll
            for (int ktl = 0; ktl < 4; ++ktl) {
                short8 Ah2[2], Am2[2], Al2[2];
#pragma unroll
                for (int il = 0; il < 2; ++il)
                    ldsA(h_hm, h_l, il * 16 + m16, ktl * 32 + quad * 8,
                         Ah2[il], Am2[il], Al2[il]);
                const int ktg = q * 4 + ktl;
                const size_t off = ((size_t)(ktg * 8 + w) * 64 + lane) * 8;
                const short8 bh = *(const short8*)(W2h + off);
                const short8 bm = *(const short8*)(W2m + off);
                const short8 bl = *(const short8*)(W2l + off);
#pragma unroll
                for (int il = 0; il < 2; ++il) {
                    floatx4 a = acc2[il];
                    MFMA6(Ah2[il], Am2[il], Al2[il], bh, bm, bl, a);
                    acc2[il] = a;
                }
            }
        }
    }

    // ---- epilogue: +b2, write eps, ent = mean_b |eps| ----
    {
        const int col = w * 16 + m16;  // nt2 = w
        const float bb2 = b2[col];
#pragma unroll
        for (int il = 0; il < 2; ++il) {
            float pa = 0.f;
#pragma unroll
            for (int r = 0; r < 4; ++r) {
                const float e = acc2[il][r] + bb2;
                const int b = quad * 4 + r;
                eps_buf[((size_t)b * 1024 + l0 + il) * 128 + col] = e;
                pa += fabsf(e);
            }
            pa += __shfl_xor(pa, 16);
            pa += __shfl_xor(pa, 32);
            if (quad == 0) ent[(l0 + il) * 128 + col] = pa * (1.0f / 16.0f);
        }
    }
}

// ------- monotone-counter grid barrier, backoff polling --------------------
// No threadfence (R8's fence cost ~8us/barrier). s_sleep(16) ~1k cyc backoff
// avoids an RMW storm on the counter line.
__device__ __forceinline__ void gbar(unsigned* c, unsigned target) {
    __syncthreads();
    if (threadIdx.x == 0) {
        atomicAdd(c, 1u);
        while (atomicAdd(c, 0u) < target) __builtin_amdgcn_s_sleep(16);
    }
    __syncthreads();
}

// -------- fused select: pools + radix top-k + per-pixel update coeffs ------
__global__ __launch_bounds__(256, 1) void select_kernel(
    const float* __restrict__ ent, float* __restrict__ p1,
    float* __restrict__ p2, float* __restrict__ p3,
    unsigned* __restrict__ ghist, unsigned* __restrict__ ctr,
    unsigned* __restrict__ gprefix, float* __restrict__ cA,
    float* __restrict__ cB, float* __restrict__ cG,
    const float* __restrict__ accum_si, float base_a, float base_b,
    float h_lam, int si) {
    __shared__ float dataL[2048];
    __shared__ unsigned hist[4][256];
    __shared__ unsigned sh[256];
    __shared__ unsigned sh_dig, sh_krem;
    const int bid = blockIdx.x, t = threadIdx.x;
    const int gid = bid * 256 + t;
    unsigned* cc = &ctr[si];

    // ---- stage block-local data (+ publish pools) ----
    int scale, nloc;
    unsigned K;
    if (bid < 64) {
        scale = 0; nloc = 2048; K = 26214u;
        const int base = bid * 2048;
        for (int i = t; i < 2048; i += 256) dataL[i] = ent[base + i];
    } else if (bid < 80) {
        scale = 1; nloc = 2048; K = 6553u;
        const int base = (bid - 64) * 2048;
        for (int i = t; i < 2048; i += 256) {
            const int idx = base + i;
            const int r = idx >> 6, c = idx & 63;
            float s = 0.f;
#pragma unroll
            for (int ii = 0; ii < 2; ++ii)
#pragma unroll
                for (int jj = 0; jj < 2; ++jj)
                    s += ent[((r * 2 + ii) << 7) + c * 2 + jj];
            const float v = s * 0.25f;
            dataL[i] = v;
            atomicExch((unsigned*)&p1[idx], __float_as_uint(v));
        }
    } else if (bid < 84) {
        scale = 2; nloc = 2048; K = 1638u;
        const int base = (bid - 80) * 2048;
        for (int i = t; i < 2048; i += 256) {
            const int idx = base + i;
            const int r = idx >> 5, c = idx & 31;
            float s = 0.f;
#pragma unroll
            for (int ii = 0; ii < 4; ++ii)
#pragma unroll
                for (int jj = 0; jj < 4; ++jj)
                    s += ent[((r * 4 + ii) << 7) + c * 4 + jj];
            const float v = s * 0.0625f;
            dataL[i] = v;
            atomicExch((unsigned*)&p2[idx], __float_as_uint(v));
        }
    } else {
        scale = 3; nloc = 512; K = 409u;
        const int base = (bid - 84) * 512;
        for (int i = t; i < 512; i += 256) {
            const int idx = base + i;
            const int r = idx >> 4, c = idx & 15;
            float s = 0.f;
#pragma unroll
            for (int ii = 0; ii < 8; ++ii)
#pragma unroll
                for (int jj = 0; jj < 8; ++jj)
                    s += ent[((r * 8 + ii) << 7) + c * 8 + jj];
            const float v = s * (1.0f / 64.0f);
            dataL[i] = v;
            atomicExch((unsigned*)&p3[idx], __float_as_uint(v));
        }
    }
    __syncthreads();  // dataL ready (block-local)

    // ---- 4-pass radix select over LDS data ----
    const int wv = t >> 6;
    unsigned prefix = 0u, krem = K;
    for (int p = 0; p < 4; ++p) {
        const int shift = 24 - 8 * p;
        const unsigned hmask = p ? (0xFFFFFFFFu << (shift + 8)) : 0u;
#pragma unroll
        for (int i = t; i < 1024; i += 256) ((unsigned*)hist)[i] = 0u;
        __syncthreads();
        for (int i = t; i < nloc; i += 256) {
            const unsigned u = fordbits(__float_as_uint(dataL[i]));
            if ((u & hmask) == (prefix & hmask))
                atomicAdd(&hist[wv][(u >> shift) & 255u], 1u);
        }
        __syncthreads();
        const unsigned c = hist[0][t] + hist[1][t] + hist[2][t] + hist[3][t];
        unsigned* gh = &ghist[((si * 4 + p) * 4 + scale) * 256];
        if (c) atomicAdd(&gh[t], c);
        gbar(cc, 88u * (unsigned)(p + 1));
        sh[t] = atomicAdd(&gh[t], 0u);
        __syncthreads();
#pragma unroll
        for (int off = 1; off < 256; off <<= 1) {
            const unsigned v = (t + off < 256) ? sh[t + off] : 0u;
            __syncthreads();
            sh[t] += v;
            __syncthreads();
        }
        const unsigned suf = sh[t];
        const unsigned sufn = (t < 255) ? sh[t + 1] : 0u;
        if (suf >= krem && sufn < krem) {  // unique crossing
            sh_dig = (unsigned)t;
            sh_krem = krem - sufn;
        }
        __syncthreads();
        prefix |= (sh_dig << shift);
        krem = sh_krem;
        __syncthreads();
    }
    // one owner block per scale publishes its threshold
    if (t == 0 && (bid == 0 || bid == 64 || bid == 80 || bid == 84))
        atomicExch(&gprefix[scale], prefix);
    gbar(cc, 88u * 5u);

    // ---- coeff maps: per pixel, z_new = cA*z - cB*eps - cG*(z-y)*m ----
    const unsigned t0 = atomicAdd(&gprefix[0], 0u);
    const unsigned t1 = atomicAdd(&gprefix[1], 0u);
    const unsigned t2 = atomicAdd(&gprefix[2], 0u);
    const unsigned t3 = atomicAdd(&gprefix[3], 0u);
    const float mean = accum_si[0] * (1.0f / (float)BLC);
    const float var = accum_si[1] * (1.0f / (float)BLC) - mean * mean;
    const float vinv = 1.0f / (var + 1e-8f);

    for (int i = gid; i < LC; i += 22528) {
        const int l = i >> 7, c = i & 127;
        float ent_v = 0.f;
        bool sel = false;
        const float v0 = ent[i];
        if (fordbits(__float_as_uint(v0)) >= t0) { ent_v = v0; sel = true; }
        else {
            const float v1 = __uint_as_float(atomicAdd(
                (unsigned*)&p1[((l >> 1) << 6) + (c >> 1)], 0u));
            if (fordbits(__float_as_uint(v1)) >= t1) { ent_v = v1; sel = true; }
            else {
                const float v2 = __uint_as_float(atomicAdd(
                    (unsigned*)&p2[((l >> 2) << 5) + (c >> 2)], 0u));
                if (fordbits(__float_as_uint(v2)) >= t2) { ent_v = v2; sel = true; }
                else {
                    const float v3 = __uint_as_float(atomicAdd(
                        (unsigned*)&p3[((l >> 3) << 4) + (c >> 3)], 0u));
                    if (fordbits(__float_as_uint(v3)) >= t3) { ent_v = v3; sel = true; }
                }
            }
        }
        if (sel) {
            float corr;
            if (ent_v > 0.5f)
                corr = 1.0f + h_lam + h_lam * h_lam * (1.0f / 3.0f);
            else if (ent_v > 0.1f)
                corr = 1.0f + 0.5f * h_lam;
            else
                corr = 1.0f;
            cA[i] = base_a;
            cB[i] = base_b * corr;
            cG[i] = (2.0f * ent_v / (ent_v + 1.0f)) * vinv;
        } else {
            cA[i] = 1.0f;
            cB[i] = 0.f;
            cG[i] = 0.f;
        }
    }
}

// ---------------- standalone final update (coeff-map streaming) ------------
__global__ __launch_bounds__(256) void update_kernel(
    float* __restrict__ z, const float* __restrict__ y,
    const float* __restrict__ mk, const float* __restrict__ eps,
    const float* __restrict__ cA, const float* __restrict__ cB,
    const float* __restrict__ cG) {
    const int idx = blockIdx.x * 256 + threadIdx.x;  // < BLC
    const int p = idx & (LC - 1);
    const float zi = z[idx];
    z[idx] = cA[p] * zi - cB[p] * eps[idx] - cG[p] * ((zi - y[idx]) * mk[idx]);
}

// ---------------------------------------------------------------------------
extern "C" void kernel_launch(void* const* d_in, const int* in_sizes, int n_in,
                              void* d_out, int out_size, void* d_ws,
                              size_t ws_size, hipStream_t stream) {
    const float* y_obs = (const float*)d_in[0];
    const float* mask = (const float*)d_in[1];
    const float* z_init = (const float*)d_in[2];
    const float* W1 = (const float*)d_in[3];
    const float* b1 = (const float*)d_in[4];
    const float* W2 = (const float*)d_in[5];
    const float* b2 = (const float*)d_in[6];
    const float* tw = (const float*)d_in[7];
    float* z = (float*)d_out;
    float* ws = (float*)d_ws;

    // workspace layout (float offsets)
    float* eps = ws;                                 // 2097152
    float* ent = ws + 2097152;                       // 131072
    float* p1 = ws + 2228224;                        // 32768
    float* p2 = ws + 2260992;                        // 8192
    float* p3 = ws + 2269184;                        // 2048
    float* cA = ws + 2271232;                        // 131072
    float* cB = ws + 2402304;                        // 131072
    float* cG = ws + 2533376;                        // 131072
    // zero block: ghist[16384] + ctr[4] + accum[8] + gprefix[4]
    unsigned* ghist = (unsigned*)(ws + 2664448);     // 16384 u32
    unsigned* ctr = (unsigned*)(ws + 2680832);       // 4
    float* accum = ws + 2680836;                     // 8 (2 per step)
    unsigned* gprefix = (unsigned*)(ws + 2680844);   // 4
    unsigned short* W1h = (unsigned short*)(ws + 2680848);  // 65536 u16 each
    unsigned short* W1m = (unsigned short*)(ws + 2713616);
    unsigned short* W1l = (unsigned short*)(ws + 2746384);
    unsigned short* W2h = (unsigned short*)(ws + 2779152);
    unsigned short* W2m = (unsigned short*)(ws + 2811920);
    unsigned short* W2l = (unsigned short*)(ws + 2844688);

    // diffusion schedule in fp32 (input-independent)
    float alpha_[1000], sigma_[1000], lam_[1000];
    {
        float ac = 1.0f;
        for (int i = 0; i < 1000; ++i) {
            const float beta = 1e-4f + (0.02f - 1e-4f) * ((float)i / 999.0f);
            ac = ac * (1.0f - beta);
            alpha_[i] = sqrtf(ac);
            sigma_[i] = sqrtf(1.0f - ac);
            lam_[i] = logf(alpha_[i]) - logf(sigma_[i]);
        }
    }
    float tf[4], hl[4], ba[4], bb[4];
    for (int si = 0; si < 4; ++si) {
        const int k = 999 - si * 250;
        const int kp = (k - 250 > 0) ? (k - 250) : 0;
        tf[si] = (float)k / 1000.0f;
        hl[si] = lam_[kp] - lam_[k];
        ba[si] = alpha_[kp] / alpha_[k];
        bb[si] = sigma_[kp] * (expf(hl[si]) - 1.0f);
    }

    hipMemsetAsync(ghist, 0, (16384 + 4 + 8 + 4) * sizeof(unsigned), stream);
    wsplit_kernel<<<512, 256, 0, stream>>>(W1, W2, W1h, W1m, W1l, W2h, W2m,
                                           W2l);

    for (int si = 0; si < 4; ++si) {
        if (si == 0) {
            mlp_kernel<0><<<512, 512, 0, stream>>>(
                z_init, z, y_obs, mask, W1h, W1m, W1l, W2h, W2m, W2l, b1, tw,
                b2, tf[0], eps, ent, cA, cB, cG, accum);
        } else {
            mlp_kernel<1><<<512, 512, 0, stream>>>(
                z, z, y_obs, mask, W1h, W1m, W1l, W2h, W2m, W2l, b1, tw, b2,
                tf[si], eps, ent, cA, cB, cG, accum + 2 * si);
        }
        select_kernel<<<88, 256, 0, stream>>>(
            ent, p1, p2, p3, ghist, ctr, gprefix, cA, cB, cG,
            accum + 2 * si, ba[si], bb[si], hl[si], si);
    }
    update_kernel<<<8192, 256, 0, stream>>>(z, y_obs, mask, eps, cA, cB, cG);
}

// Round 13
// 433.938 us; speedup vs baseline: 1.2427x; 1.0746x over previous
//
#include <hip/hip_runtime.h>
#include <math.h>
#include <stdint.h>

#define L_DIM 1024
#define C_DIM 128
#define H_DIM 512
#define B_DIM 16
#define LC (L_DIM * C_DIM)      // 131072
#define BLC (B_DIM * LC)        // 2097152

typedef __attribute__((ext_vector_type(8))) short short8;
typedef __attribute__((ext_vector_type(4))) float floatx4;

// ---------------- monotone float/bits -> ordered uint ----------------------
__device__ __forceinline__ unsigned fordbits(unsigned u) {
    return (u & 0x80000000u) ? ~u : (u | 0x80000000u);
}

// ---------------- truncation 3-way bf16 split: x = h + m + l + O(2^-24 x) --
__device__ __forceinline__ void split3(float x, unsigned& uh, unsigned& um,
                                       unsigned& ul) {
    uh = __float_as_uint(x);
    const float r1 = x - __uint_as_float(uh & 0xffff0000u);
    um = __float_as_uint(r1);
    const float r2 = r1 - __uint_as_float(um & 0xffff0000u);
    ul = __float_as_uint(r2);
}

__device__ __forceinline__ float gelu_fast(float x) {
    const float g = 0.7978845608028654f * (x + 0.044715f * x * x * x);
    const float e = __expf(2.0f * g);
    const float t = 1.0f - 2.0f / (e + 1.0f);
    return 0.5f * x * (1.0f + t);
}

// ---------------- W pre-split into MFMA B-frag layout (h/m/l bf16) ---------
__global__ __launch_bounds__(256) void wsplit_kernel(
    const float* __restrict__ W1, const float* __restrict__ W2,
    unsigned short* __restrict__ W1h, unsigned short* __restrict__ W1m,
    unsigned short* __restrict__ W1l, unsigned short* __restrict__ W2h,
    unsigned short* __restrict__ W2m, unsigned short* __restrict__ W2l) {
    const int t = blockIdx.x * 256 + threadIdx.x;  // < 131072
    unsigned uh, um, ul;
    if (t < 65536) {
        const int j = t & 7, lane = (t >> 3) & 63, nt = (t >> 9) & 31,
                  kt = (t >> 14) & 3;
        const int k = kt * 32 + (lane >> 4) * 8 + j;
        const int n = nt * 16 + (lane & 15);
        split3(W1[k * 512 + n], uh, um, ul);
        W1h[t] = (unsigned short)(uh >> 16);
        W1m[t] = (unsigned short)(um >> 16);
        W1l[t] = (unsigned short)(ul >> 16);
    } else {
        const int t2 = t - 65536;
        const int j = t2 & 7, lane = (t2 >> 3) & 63, nt = (t2 >> 9) & 7,
                  kt = (t2 >> 12) & 15;
        const int k = kt * 32 + (lane >> 4) * 8 + j;
        const int n = nt * 16 + (lane & 15);
        split3(W2[k * 128 + n], uh, um, ul);
        W2h[t2] = (unsigned short)(uh >> 16);
        W2m[t2] = (unsigned short)(um >> 16);
        W2l[t2] = (unsigned short)(ul >> 16);
    }
}

// 6-term bf16x3 MFMA accumulate (small terms first); error ~2^-24
#define MFMA6(AH, AM, AL, BH, BM, BL, ACC)                                    \
    ACC = __builtin_amdgcn_mfma_f32_16x16x32_bf16(AL, BH, ACC, 0, 0, 0);      \
    ACC = __builtin_amdgcn_mfma_f32_16x16x32_bf16(AM, BM, ACC, 0, 0, 0);      \
    ACC = __builtin_amdgcn_mfma_f32_16x16x32_bf16(AH, BL, ACC, 0, 0, 0);      \
    ACC = __builtin_amdgcn_mfma_f32_16x16x32_bf16(AM, BH, ACC, 0, 0, 0);      \
    ACC = __builtin_amdgcn_mfma_f32_16x16x32_bf16(AH, BM, ACC, 0, 0, 0);      \
    ACC = __builtin_amdgcn_mfma_f32_16x16x32_bf16(AH, BH, ACC, 0, 0, 0);

// XOR-swizzled LDS address: 32 rows x 128 cols of ushort per plane.
// Measured 0 bank-conflict cycles (R9/R10); frag reads are ds_read_b128.
__device__ __forceinline__ int swz(int row, int col) {
    return row * 128 + ((((col >> 3) ^ (row & 15))) << 3) + (col & 7);
}

// ---------------- fused MLP (+ previous step's DPM update when UPD) --------
// 512 thr (8 waves), M=32 rows (16b x 2l), grid 512, lb(512,4) -> VGPR<=128,
// 2 blocks/CU. Swizzled 3-plane LDS (no unpack VALU, 0 conflicts) + explicit
// double-buffered W prefetch: kt+1's W frags are loaded before kt's MFMAs so
// the compiler emits vmcnt(6)-style waits instead of serializing on each W
// load (R12: VGPR 44, no pipelining, MfmaUtil 13% = W-latency-bound).
template <int UPD>
__global__ __launch_bounds__(512, 4) void mlp_kernel(
    const float* __restrict__ zin, float* __restrict__ z,
    const float* __restrict__ y, const float* __restrict__ mk,
    const unsigned short* __restrict__ W1h, const unsigned short* __restrict__ W1m,
    const unsigned short* __restrict__ W1l, const unsigned short* __restrict__ W2h,
    const unsigned short* __restrict__ W2m, const unsigned short* __restrict__ W2l,
    const float* __restrict__ b1, const float* __restrict__ tw,
    const float* __restrict__ b2, float t_feat,
    float* __restrict__ eps_buf, float* __restrict__ ent,
    const float* __restrict__ cA, const float* __restrict__ cB,
    const float* __restrict__ cG, float* __restrict__ accum) {
    __shared__ unsigned short zA[3][4096];  // z frags, swizzled [row<32][col<128]
    __shared__ unsigned short hA[3][4096];  // h quarter frags, swizzled
    __shared__ float red1[8], red2[8];
    const int tid = threadIdx.x;
    const int w = tid >> 6, lane = tid & 63;
    const int quad = lane >> 4, m16 = lane & 15;
    const int l0 = blockIdx.x * 2;

    // ---- phase 1: (coeff-map update / init-copy) + stats + stage z ----
    float s1 = 0.f, s2 = 0.f;
#pragma unroll
    for (int e = 0; e < 2; ++e) {
        const int f = tid * 8 + e * 4;  // 0..4095
        const int r_ = f >> 7, cb = f & 127;
        const int b = r_ & 15, il = r_ >> 4, l = l0 + il;
        const size_t g = ((size_t)b * 1024 + l) * 128 + cb;
        float4 zv = *(const float4*)(zin + g);
        const float4 yv = *(const float4*)(y + g);
        const float4 mv = *(const float4*)(mk + g);
        if (UPD) {
            const float4 ev = *(const float4*)(eps_buf + g);
            const int pix = l * 128 + cb;
            const float4 a4 = *(const float4*)(cA + pix);
            const float4 b4 = *(const float4*)(cB + pix);
            const float4 g4 = *(const float4*)(cG + pix);
            zv.x = a4.x * zv.x - b4.x * ev.x - g4.x * ((zv.x - yv.x) * mv.x);
            zv.y = a4.y * zv.y - b4.y * ev.y - g4.y * ((zv.y - yv.y) * mv.y);
            zv.z = a4.z * zv.z - b4.z * ev.z - g4.z * ((zv.z - yv.z) * mv.z);
            zv.w = a4.w * zv.w - b4.w * ev.w - g4.w * ((zv.w - yv.w) * mv.w);
        }
        *(float4*)(z + g) = zv;  // UPD: updated value; !UPD: init copy
        float oe;
        oe = (zv.x - yv.x) * mv.x; s1 += oe; s2 += oe * oe;
        oe = (zv.y - yv.y) * mv.y; s1 += oe; s2 += oe * oe;
        oe = (zv.z - yv.z) * mv.z; s1 += oe; s2 += oe * oe;
        oe = (zv.w - yv.w) * mv.w; s1 += oe; s2 += oe * oe;

        const int base = swz(r_, cb);  // cb % 4 == 0 -> ushort4 stays in chunk
        const float xs[4] = {zv.x, zv.y, zv.z, zv.w};
        ushort4 vh, vm, vl;
        unsigned uh, um, ul;
        split3(xs[0], uh, um, ul); vh.x = uh >> 16; vm.x = um >> 16; vl.x = ul >> 16;
        split3(xs[1], uh, um, ul); vh.y = uh >> 16; vm.y = um >> 16; vl.y = ul >> 16;
        split3(xs[2], uh, um, ul); vh.z = uh >> 16; vm.z = um >> 16; vl.z = ul >> 16;
        split3(xs[3], uh, um, ul); vh.w = uh >> 16; vm.w = um >> 16; vl.w = ul >> 16;
        *(ushort4*)(&zA[0][base]) = vh;
        *(ushort4*)(&zA[1][base]) = vm;
        *(ushort4*)(&zA[2][base]) = vl;
    }
#pragma unroll
    for (int off = 32; off; off >>= 1) {
        s1 += __shfl_down(s1, off);
        s2 += __shfl_down(s2, off);
    }
    if (lane == 0) { red1[w] = s1; red2[w] = s2; }
    __syncthreads();  // staging + red arrays complete
    if (tid == 0) {
        float a1 = 0.f, a2 = 0.f;
#pragma unroll
        for (int i = 0; i < 8; ++i) { a1 += red1[i]; a2 += red2[i]; }
        atomicAdd(&accum[0], a1);
        atomicAdd(&accum[1], a2);
    }

    // ---- GEMM pipeline: halves over H, W double-buffer prefetch ----
    floatx4 acc2[2];
    acc2[0] = (floatx4){0.f, 0.f, 0.f, 0.f};
    acc2[1] = (floatx4){0.f, 0.f, 0.f, 0.f};

    for (int hf = 0; hf < 2; ++hf) {
        floatx4 acc1[4];  // [s*2 + il]
#pragma unroll
        for (int i = 0; i < 4; ++i) acc1[i] = (floatx4){0.f, 0.f, 0.f, 0.f};

        short8 Wb[2][2][3];  // [buf][s][h/m/l]
#pragma unroll
        for (int s = 0; s < 2; ++s) {  // preload kt=0
            const int nt1 = (hf * 2 + s) * 8 + w;
            const size_t off = ((size_t)nt1 * 64 + lane) * 8;
            Wb[0][s][0] = *(const short8*)(W1h + off);
            Wb[0][s][1] = *(const short8*)(W1m + off);
            Wb[0][s][2] = *(const short8*)(W1l + off);
        }
#pragma unroll
        for (int kt = 0; kt < 4; ++kt) {
            const int cur = kt & 1;
            if (kt < 3) {  // prefetch kt+1 before this kt's MFMAs
#pragma unroll
                for (int s = 0; s < 2; ++s) {
                    const int nt1 = (hf * 2 + s) * 8 + w;
                    const size_t off =
                        ((size_t)((kt + 1) * 32 + nt1) * 64 + lane) * 8;
                    Wb[cur ^ 1][s][0] = *(const short8*)(W1h + off);
                    Wb[cur ^ 1][s][1] = *(const short8*)(W1m + off);
                    Wb[cur ^ 1][s][2] = *(const short8*)(W1l + off);
                }
            }
            short8 Ah[2], Am[2], Al[2];
#pragma unroll
            for (int il = 0; il < 2; ++il) {
                const int fb = swz(il * 16 + m16, kt * 32 + quad * 8);
                Ah[il] = *(const short8*)(&zA[0][fb]);
                Am[il] = *(const short8*)(&zA[1][fb]);
                Al[il] = *(const short8*)(&zA[2][fb]);
            }
#pragma unroll
            for (int s = 0; s < 2; ++s) {
#pragma unroll
                for (int il = 0; il < 2; ++il) {
                    floatx4 a = acc1[s * 2 + il];
                    MFMA6(Ah[il], Am[il], Al[il], Wb[cur][s][0], Wb[cur][s][1],
                          Wb[cur][s][2], a);
                    acc1[s * 2 + il] = a;
                }
            }
        }

#pragma unroll
        for (int s = 0; s < 2; ++s) {
            const int q = hf * 2 + s;
            short8 W2b[2][3];
            {  // preload (q, ktl=0); issued before barriers (no LDS dep)
                const size_t off0 = ((size_t)((q * 4) * 8 + w) * 64 + lane) * 8;
                W2b[0][0] = *(const short8*)(W2h + off0);
                W2b[0][1] = *(const short8*)(W2m + off0);
                W2b[0][2] = *(const short8*)(W2l + off0);
            }
            __syncthreads();  // previous quarter's hA reads done
            {
                const int kcol = w * 16 + m16;     // quarter-local k col
                const int colg = q * 128 + kcol;   // global H col
                const float bb = b1[colg] + t_feat * tw[colg];
#pragma unroll
                for (int il = 0; il < 2; ++il) {
#pragma unroll
                    for (int r = 0; r < 4; ++r) {
                        const float x = gelu_fast(acc1[s * 2 + il][r] + bb);
                        unsigned uh, um, ul;
                        split3(x, uh, um, ul);
                        const int idx = swz(il * 16 + quad * 4 + r, kcol);
                        hA[0][idx] = (unsigned short)(uh >> 16);
                        hA[1][idx] = (unsigned short)(um >> 16);
                        hA[2][idx] = (unsigned short)(ul >> 16);
                    }
                }
            }
            __syncthreads();

#pragma unroll
            for (int ktl = 0; ktl < 4; ++ktl) {
                const int cur = ktl & 1;
                if (ktl < 3) {  // prefetch ktl+1
                    const size_t offn =
                        ((size_t)((q * 4 + ktl + 1) * 8 + w) * 64 + lane) * 8;
                    W2b[cur ^ 1][0] = *(const short8*)(W2h + offn);
                    W2b[cur ^ 1][1] = *(const short8*)(W2m + offn);
                    W2b[cur ^ 1][2] = *(const short8*)(W2l + offn);
                }
                short8 Ah2[2], Am2[2], Al2[2];
#pragma unroll
                for (int il = 0; il < 2; ++il) {
                    const int fb = swz(il * 16 + m16, ktl * 32 + quad * 8);
                    Ah2[il] = *(const short8*)(&hA[0][fb]);
                    Am2[il] = *(const short8*)(&hA[1][fb]);
                    Al2[il] = *(const short8*)(&hA[2][fb]);
                }
#pragma unroll
                for (int il = 0; il < 2; ++il) {
                    floatx4 a = acc2[il];
                    MFMA6(Ah2[il], Am2[il], Al2[il], W2b[cur][0], W2b[cur][1],
                          W2b[cur][2], a);
                    acc2[il] = a;
                }
            }
        }
    }

    // ---- epilogue: +b2, write eps, ent = mean_b |eps| ----
    {
        const int col = w * 16 + m16;  // nt2 = w
        const float bb2 = b2[col];
#pragma unroll
        for (int il = 0; il < 2; ++il) {
            float pa = 0.f;
#pragma unroll
            for (int r = 0; r < 4; ++r) {
                const float e = acc2[il][r] + bb2;
                const int b = quad * 4 + r;
                eps_buf[((size_t)b * 1024 + l0 + il) * 128 + col] = e;
                pa += fabsf(e);
            }
            pa += __shfl_xor(pa, 16);
            pa += __shfl_xor(pa, 32);
            if (quad == 0) ent[(l0 + il) * 128 + col] = pa * (1.0f / 16.0f);
        }
    }
}

// ------- monotone-counter grid barrier, backoff polling --------------------
__device__ __forceinline__ void gbar(unsigned* c, unsigned target) {
    __syncthreads();
    if (threadIdx.x == 0) {
        atomicAdd(c, 1u);
        while (atomicAdd(c, 0u) < target) __builtin_amdgcn_s_sleep(16);
    }
    __syncthreads();
}

// -------- fused select: pools + radix top-k + per-pixel update coeffs ------
__global__ __launch_bounds__(256, 1) void select_kernel(
    const float* __restrict__ ent, float* __restrict__ p1,
    float* __restrict__ p2, float* __restrict__ p3,
    unsigned* __restrict__ ghist, unsigned* __restrict__ ctr,
    unsigned* __restrict__ gprefix, float* __restrict__ cA,
    float* __restrict__ cB, float* __restrict__ cG,
    const float* __restrict__ accum_si, float base_a, float base_b,
    float h_lam, int si) {
    __shared__ float dataL[2048];
    __shared__ unsigned hist[4][256];
    __shared__ unsigned sh[256];
    __shared__ unsigned sh_dig, sh_krem;
    const int bid = blockIdx.x, t = threadIdx.x;
    const int gid = bid * 256 + t;
    unsigned* cc = &ctr[si];

    // ---- stage block-local data (+ publish pools) ----
    int scale, nloc;
    unsigned K;
    if (bid < 64) {
        scale = 0; nloc = 2048; K = 26214u;
        const int base = bid * 2048;
        for (int i = t; i < 2048; i += 256) dataL[i] = ent[base + i];
    } else if (bid < 80) {
        scale = 1; nloc = 2048; K = 6553u;
        const int base = (bid - 64) * 2048;
        for (int i = t; i < 2048; i += 256) {
            const int idx = base + i;
            const int r = idx >> 6, c = idx & 63;
            float s = 0.f;
#pragma unroll
            for (int ii = 0; ii < 2; ++ii)
#pragma unroll
                for (int jj = 0; jj < 2; ++jj)
                    s += ent[((r * 2 + ii) << 7) + c * 2 + jj];
            const float v = s * 0.25f;
            dataL[i] = v;
            atomicExch((unsigned*)&p1[idx], __float_as_uint(v));
        }
    } else if (bid < 84) {
        scale = 2; nloc = 2048; K = 1638u;
        const int base = (bid - 80) * 2048;
        for (int i = t; i < 2048; i += 256) {
            const int idx = base + i;
            const int r = idx >> 5, c = idx & 31;
            float s = 0.f;
#pragma unroll
            for (int ii = 0; ii < 4; ++ii)
#pragma unroll
                for (int jj = 0; jj < 4; ++jj)
                    s += ent[((r * 4 + ii) << 7) + c * 4 + jj];
            const float v = s * 0.0625f;
            dataL[i] = v;
            atomicExch((unsigned*)&p2[idx], __float_as_uint(v));
        }
    } else {
        scale = 3; nloc = 512; K = 409u;
        const int base = (bid - 84) * 512;
        for (int i = t; i < 512; i += 256) {
            const int idx = base + i;
            const int r = idx >> 4, c = idx & 15;
            float s = 0.f;
#pragma unroll
            for (int ii = 0; ii < 8; ++ii)
#pragma unroll
                for (int jj = 0; jj < 8; ++jj)
                    s += ent[((r * 8 + ii) << 7) + c * 8 + jj];
            const float v = s * (1.0f / 64.0f);
            dataL[i] = v;
            atomicExch((unsigned*)&p3[idx], __float_as_uint(v));
        }
    }
    __syncthreads();  // dataL ready (block-local)

    // ---- 4-pass radix select over LDS data ----
    const int wv = t >> 6;
    unsigned prefix = 0u, krem = K;
    for (int p = 0; p < 4; ++p) {
        const int shift = 24 - 8 * p;
        const unsigned hmask = p ? (0xFFFFFFFFu << (shift + 8)) : 0u;
#pragma unroll
        for (int i = t; i < 1024; i += 256) ((unsigned*)hist)[i] = 0u;
        __syncthreads();
        for (int i = t; i < nloc; i += 256) {
            const unsigned u = fordbits(__float_as_uint(dataL[i]));
            if ((u & hmask) == (prefix & hmask))
                atomicAdd(&hist[wv][(u >> shift) & 255u], 1u);
        }
        __syncthreads();
        const unsigned c = hist[0][t] + hist[1][t] + hist[2][t] + hist[3][t];
        unsigned* gh = &ghist[((si * 4 + p) * 4 + scale) * 256];
        if (c) atomicAdd(&gh[t], c);
        gbar(cc, 88u * (unsigned)(p + 1));
        sh[t] = atomicAdd(&gh[t], 0u);
        __syncthreads();
#pragma unroll
        for (int off = 1; off < 256; off <<= 1) {
            const unsigned v = (t + off < 256) ? sh[t + off] : 0u;
            __syncthreads();
            sh[t] += v;
            __syncthreads();
        }
        const unsigned suf = sh[t];
        const unsigned sufn = (t < 255) ? sh[t + 1] : 0u;
        if (suf >= krem && sufn < krem) {  // unique crossing
            sh_dig = (unsigned)t;
            sh_krem = krem - sufn;
        }
        __syncthreads();
        prefix |= (sh_dig << shift);
        krem = sh_krem;
        __syncthreads();
    }
    // one owner block per scale publishes its threshold
    if (t == 0 && (bid == 0 || bid == 64 || bid == 80 || bid == 84))
        atomicExch(&gprefix[scale], prefix);
    gbar(cc, 88u * 5u);

    // ---- coeff maps: per pixel, z_new = cA*z - cB*eps - cG*(z-y)*m ----
    const unsigned t0 = atomicAdd(&gprefix[0], 0u);
    const unsigned t1 = atomicAdd(&gprefix[1], 0u);
    const unsigned t2 = atomicAdd(&gprefix[2], 0u);
    const unsigned t3 = atomicAdd(&gprefix[3], 0u);
    const float mean = accum_si[0] * (1.0f / (float)BLC);
    const float var = accum_si[1] * (1.0f / (float)BLC) - mean * mean;
    const float vinv = 1.0f / (var + 1e-8f);

    for (int i = gid; i < LC; i += 22528) {
        const int l = i >> 7, c = i & 127;
        float ent_v = 0.f;
        bool sel = false;
        const float v0 = ent[i];
        if (fordbits(__float_as_uint(v0)) >= t0) { ent_v = v0; sel = true; }
        else {
            const float v1 = __uint_as_float(atomicAdd(
                (unsigned*)&p1[((l >> 1) << 6) + (c >> 1)], 0u));
            if (fordbits(__float_as_uint(v1)) >= t1) { ent_v = v1; sel = true; }
            else {
                const float v2 = __uint_as_float(atomicAdd(
                    (unsigned*)&p2[((l >> 2) << 5) + (c >> 2)], 0u));
                if (fordbits(__float_as_uint(v2)) >= t2) { ent_v = v2; sel = true; }
                else {
                    const float v3 = __uint_as_float(atomicAdd(
                        (unsigned*)&p3[((l >> 3) << 4) + (c >> 3)], 0u));
                    if (fordbits(__float_as_uint(v3)) >= t3) { ent_v = v3; sel = true; }
                }
            }
        }
        if (sel) {
            float corr;
            if (ent_v > 0.5f)
                corr = 1.0f + h_lam + h_lam * h_lam * (1.0f / 3.0f);
            else if (ent_v > 0.1f)
                corr = 1.0f + 0.5f * h_lam;
            else
                corr = 1.0f;
            cA[i] = base_a;
            cB[i] = base_b * corr;
            cG[i] = (2.0f * ent_v / (ent_v + 1.0f)) * vinv;
        } else {
            cA[i] = 1.0f;
            cB[i] = 0.f;
            cG[i] = 0.f;
        }
    }
}

// ---------------- standalone final update (coeff-map streaming) ------------
__global__ __launch_bounds__(256) void update_kernel(
    float* __restrict__ z, const float* __restrict__ y,
    const float* __restrict__ mk, const float* __restrict__ eps,
    const float* __restrict__ cA, const float* __restrict__ cB,
    const float* __restrict__ cG) {
    const int idx = blockIdx.x * 256 + threadIdx.x;  // < BLC
    const int p = idx & (LC - 1);
    const float zi = z[idx];
    z[idx] = cA[p] * zi - cB[p] * eps[idx] - cG[p] * ((zi - y[idx]) * mk[idx]);
}

// ---------------------------------------------------------------------------
extern "C" void kernel_launch(void* const* d_in, const int* in_sizes, int n_in,
                              void* d_out, int out_size, void* d_ws,
                              size_t ws_size, hipStream_t stream) {
    const float* y_obs = (const float*)d_in[0];
    const float* mask = (const float*)d_in[1];
    const float* z_init = (const float*)d_in[2];
    const float* W1 = (const float*)d_in[3];
    const float* b1 = (const float*)d_in[4];
    const float* W2 = (const float*)d_in[5];
    const float* b2 = (const float*)d_in[6];
    const float* tw = (const float*)d_in[7];
    float* z = (float*)d_out;
    float* ws = (float*)d_ws;

    // workspace layout (float offsets)
    float* eps = ws;                                 // 2097152
    float* ent = ws + 2097152;                       // 131072
    float* p1 = ws + 2228224;                        // 32768
    float* p2 = ws + 2260992;                        // 8192
    float* p3 = ws + 2269184;                        // 2048
    float* cA = ws + 2271232;                        // 131072
    float* cB = ws + 2402304;                        // 131072
    float* cG = ws + 2533376;                        // 131072
    // zero block: ghist[16384] + ctr[4] + accum[8] + gprefix[4]
    unsigned* ghist = (unsigned*)(ws + 2664448);     // 16384 u32
    unsigned* ctr = (unsigned*)(ws + 2680832);       // 4
    float* accum = ws + 2680836;                     // 8 (2 per step)
    unsigned* gprefix = (unsigned*)(ws + 2680844);   // 4
    unsigned short* W1h = (unsigned short*)(ws + 2680848);  // 65536 u16 each
    unsigned short* W1m = (unsigned short*)(ws + 2713616);
    unsigned short* W1l = (unsigned short*)(ws + 2746384);
    unsigned short* W2h = (unsigned short*)(ws + 2779152);
    unsigned short* W2m = (unsigned short*)(ws + 2811920);
    unsigned short* W2l = (unsigned short*)(ws + 2844688);

    // diffusion schedule in fp32 (input-independent)
    float alpha_[1000], sigma_[1000], lam_[1000];
    {
        float ac = 1.0f;
        for (int i = 0; i < 1000; ++i) {
            const float beta = 1e-4f + (0.02f - 1e-4f) * ((float)i / 999.0f);
            ac = ac * (1.0f - beta);
            alpha_[i] = sqrtf(ac);
            sigma_[i] = sqrtf(1.0f - ac);
            lam_[i] = logf(alpha_[i]) - logf(sigma_[i]);
        }
    }
    float tf[4], hl[4], ba[4], bb[4];
    for (int si = 0; si < 4; ++si) {
        const int k = 999 - si * 250;
        const int kp = (k - 250 > 0) ? (k - 250) : 0;
        tf[si] = (float)k / 1000.0f;
        hl[si] = lam_[kp] - lam_[k];
        ba[si] = alpha_[kp] / alpha_[k];
        bb[si] = sigma_[kp] * (expf(hl[si]) - 1.0f);
    }

    hipMemsetAsync(ghist, 0, (16384 + 4 + 8 + 4) * sizeof(unsigned), stream);
    wsplit_kernel<<<512, 256, 0, stream>>>(W1, W2, W1h, W1m, W1l, W2h, W2m,
                                           W2l);

    for (int si = 0; si < 4; ++si) {
        if (si == 0) {
            mlp_kernel<0><<<512, 512, 0, stream>>>(
                z_init, z, y_obs, mask, W1h, W1m, W1l, W2h, W2m, W2l, b1, tw,
                b2, tf[0], eps, ent, cA, cB, cG, accum);
        } else {
            mlp_kernel<1><<<512, 512, 0, stream>>>(
                z, z, y_obs, mask, W1h, W1m, W1l, W2h, W2m, W2l, b1, tw, b2,
                tf[si], eps, ent, cA, cB, cG, accum + 2 * si);
        }
        select_kernel<<<88, 256, 0, stream>>>(
            ent, p1, p2, p3, ghist, ctr, gprefix, cA, cB, cG,
            accum + 2 * si, ba[si], bb[si], hl[si], si);
    }
    update_kernel<<<8192, 256, 0, stream>>>(z, y_obs, mask, eps, cA, cB, cG);
}